// Round 14
// baseline (101.758 us; speedup 1.0000x reference)
//
#include <hip/hip_runtime.h>
#include <math.h>

// NoisyTopkRouter: B=4 S=4096 D=2048 E=16 K=2, TEMPERATURE=1. rows = 16384.
// out layout (fp32): router_output [16384*16] | indices-as-float [16384*2] | aux_loss [1]
// Round 14: RC=64 geometry + vmcnt-FIFO-safe issue order.
//  k1: 128 rowtiles x 2 dslices (grid 256), 512 thr (8 waves x 128-d slice).
//   - lane = (rg 0..15, q 0..3): R=8 rows (rg+16i) x C=8 experts (q<2 route
//     8q.., q>=2 noise). One ds_read_b128 feeds 32 FMAs -> DS pipe halved.
//   - per-chunk (8 d) issue order: [W-even(8)] [write xp_prev: vmcnt(8), W
//     stays in flight] [FMA-even] [W-odd(8)] [xp_next AFTER W-odd] [FMA-odd:
//     vmcnt(4), xp stays in flight]. No wait drains the x HBM prefetch (the
//     in-order vmcnt FIFO coupling diagnosed from r9-r13's invariant ~52us).
//   - single per-wave x buffer [128][8], write-before-read (same-wave lgkm),
//     XOR quad swizzle (squad ^ ((row>>2)&1)): reads 2-way = free.
//   - 64KB LDS declared (32KB x live; reduce uses all 64KB) -> 2-block budget
//     target -> 128 VGPR >= ~124 demand (rule fitted r3..r13).
//  k2 epilogue (r13-proven), k3 aux.

#define DDIM 2048
#define NEXP 16
#define ROWS 128           // rows per block
#define BLK_D 1024         // d half per block (NS=2)
#define WAVE_D 128         // d per wave
#define NCHNK 16           // 8-d chunks per wave
#define IDX_OFF 262144
#define AUX_OFF 294912

__global__ __launch_bounds__(512) void gemv_k(
    const float* __restrict__ x, const float* __restrict__ wr,
    const float* __restrict__ wn, float* __restrict__ pbase) {
  __shared__ float smem[16384];  // 64KB: 8 x-regions [128][8] / 4 reduce regions [128][32]

  const int tid  = threadIdx.x;
  const int wave = tid >> 6;
  const int lane = tid & 63;
  const int rg   = lane >> 2;        // 0..15 -> rows {rg + 16i}, i = 0..7
  const int q    = lane & 3;         // q<2: route experts 8q..; q>=2: noise 8(q-2)..
  const int rsw  = (rg >> 2) & 1;    // read-side quad swizzle bit
  const int rowtile = blockIdx.x >> 1;
  const int dslice  = blockIdx.x & 1;
  const int row_base = rowtile * ROWS;
  const int d_base   = dslice * BLK_D + wave * WAVE_D;

  float* xreg = smem + wave * 1024;  // [128][8] single buffer (per-wave private)

  // staging: lane -> (srow = lane>>1, squad = lane&1); rows srow + 32t, t=0..3
  const int srow  = lane >> 1;
  const int squad = lane & 1;
  const float* xsrc = x + (size_t)(row_base + srow) * DDIM + d_base + squad * 4;
  const int woff = srow * 8 + ((squad ^ ((srow >> 2) & 1)) << 2);  // +256 per t

  const float* wbase = (q < 2 ? wr : wn) + (size_t)d_base * NEXP + (q & 1) * 8;

  // acc[2i+j]: row rg+16i, expert quad j of this lane's 8 experts
  float4 acc[16];
  #pragma unroll
  for (int i = 0; i < 16; ++i) acc[i] = make_float4(0.f, 0.f, 0.f, 0.f);

  float4 xp[4];
  #pragma unroll
  for (int t = 0; t < 4; ++t) xp[t] = *(const float4*)(xsrc + (size_t)t * 32 * DDIM);

// 32 fmaf for row i against W regs w00..w31 (4 d x 8 experts)
#define FMA_BLK(i, GGS) { \
    const float4 xv = *(const float4*)(xb + (rg + 16 * (i)) * 8 + ((GGS) << 2)); \
    acc[2*(i)  ].x = fmaf(xv.w,w30.x,fmaf(xv.z,w20.x,fmaf(xv.y,w10.x,fmaf(xv.x,w00.x,acc[2*(i)  ].x)))); \
    acc[2*(i)  ].y = fmaf(xv.w,w30.y,fmaf(xv.z,w20.y,fmaf(xv.y,w10.y,fmaf(xv.x,w00.y,acc[2*(i)  ].y)))); \
    acc[2*(i)  ].z = fmaf(xv.w,w30.z,fmaf(xv.z,w20.z,fmaf(xv.y,w10.z,fmaf(xv.x,w00.z,acc[2*(i)  ].z)))); \
    acc[2*(i)  ].w = fmaf(xv.w,w30.w,fmaf(xv.z,w20.w,fmaf(xv.y,w10.w,fmaf(xv.x,w00.w,acc[2*(i)  ].w)))); \
    acc[2*(i)+1].x = fmaf(xv.w,w31.x,fmaf(xv.z,w21.x,fmaf(xv.y,w11.x,fmaf(xv.x,w01.x,acc[2*(i)+1].x)))); \
    acc[2*(i)+1].y = fmaf(xv.w,w31.y,fmaf(xv.z,w21.y,fmaf(xv.y,w11.y,fmaf(xv.x,w01.y,acc[2*(i)+1].y)))); \
    acc[2*(i)+1].z = fmaf(xv.w,w31.z,fmaf(xv.z,w21.z,fmaf(xv.y,w11.z,fmaf(xv.x,w01.z,acc[2*(i)+1].z)))); \
    acc[2*(i)+1].w = fmaf(xv.w,w31.w,fmaf(xv.z,w21.w,fmaf(xv.y,w11.w,fmaf(xv.x,w01.w,acc[2*(i)+1].w)))); }

  for (int k = 0; k < NCHNK; ++k) {
    const float* xb = xreg;
    // ---- W-even loads (group 2k: d = 8k..8k+3) ----
    const float* wle = wbase + (size_t)(8 * k) * NEXP;
    float4 w00 = *(const float4*)(wle +  0), w01 = *(const float4*)(wle +  4);
    float4 w10 = *(const float4*)(wle + 16), w11 = *(const float4*)(wle + 20);
    float4 w20 = *(const float4*)(wle + 32), w21 = *(const float4*)(wle + 36);
    float4 w30 = *(const float4*)(wle + 48), w31 = *(const float4*)(wle + 52);
    // ---- write this chunk's staged x (xp loaded last iter; waits vmcnt(8):
    //      W-even stays in flight, no HBM drain) ----
    #pragma unroll
    for (int t = 0; t < 4; ++t) *(float4*)(xreg + woff + t * 256) = xp[t];
    // ---- FMA even (compiler inserts lgkm wait for ds_write->ds_read) ----
    #pragma unroll
    for (int i = 0; i < 8; ++i) FMA_BLK(i, rsw);
    // ---- W-odd loads (group 2k+1: d = 8k+4..8k+7) ----
    const float* wlo = wbase + (size_t)(8 * k + 4) * NEXP;
    w00 = *(const float4*)(wlo +  0); w01 = *(const float4*)(wlo +  4);
    w10 = *(const float4*)(wlo + 16); w11 = *(const float4*)(wlo + 20);
    w20 = *(const float4*)(wlo + 32); w21 = *(const float4*)(wlo + 36);
    w30 = *(const float4*)(wlo + 48); w31 = *(const float4*)(wlo + 52);
    // ---- x prefetch chunk k+1, issued AFTER W-odd (FIFO: W-odd wait won't
    //      drain it; its own wait happens next iter at the write, vmcnt(8)) ----
    if (k + 1 < NCHNK) {
      #pragma unroll
      for (int t = 0; t < 4; ++t)
        xp[t] = *(const float4*)(xsrc + (size_t)t * 32 * DDIM + (k + 1) * 8);
    }
    // ---- FMA odd (waits W-odd at vmcnt(4); xp stays in flight) ----
    #pragma unroll
    for (int i = 0; i < 8; ++i) FMA_BLK(i, 1 ^ rsw);
  }

  // ---- 8-wave tree reduce over 4 x [128][32] regions (slot XOR rg&7) ----
#define DUMP_R(Rg) { float* pr = smem + (Rg) * 4096; \
    _Pragma("unroll") for (int i = 0; i < 8; ++i) { \
      *(float4*)(pr + (rg + 16*i) * 32 + ((((q<<1)+0) ^ (rg&7)) << 2)) = acc[2*i]; \
      *(float4*)(pr + (rg + 16*i) * 32 + ((((q<<1)+1) ^ (rg&7)) << 2)) = acc[2*i+1]; } }
#define ADD_R(Rg) { const float* pr = smem + (Rg) * 4096; \
    _Pragma("unroll") for (int i = 0; i < 8; ++i) { \
      float4 a0 = *(const float4*)(pr + (rg + 16*i) * 32 + ((((q<<1)+0) ^ (rg&7)) << 2)); \
      float4 a1 = *(const float4*)(pr + (rg + 16*i) * 32 + ((((q<<1)+1) ^ (rg&7)) << 2)); \
      acc[2*i  ].x += a0.x; acc[2*i  ].y += a0.y; acc[2*i  ].z += a0.z; acc[2*i  ].w += a0.w; \
      acc[2*i+1].x += a1.x; acc[2*i+1].y += a1.y; acc[2*i+1].z += a1.z; acc[2*i+1].w += a1.w; } }

  __syncthreads();
  if (wave >= 4) DUMP_R(wave - 4);
  __syncthreads();
  if (wave < 4)  ADD_R(wave);
  __syncthreads();
  if (wave >= 2 && wave < 4) DUMP_R(wave - 2);
  __syncthreads();
  if (wave < 2)  ADD_R(wave);
  __syncthreads();
  if (wave == 1) DUMP_R(0);
  __syncthreads();

  // ---- wave 0: final add, write partial [128][32] to workspace from regs ----
  if (wave == 0) {
    ADD_R(0);
    float* pws = pbase + (size_t)(dslice * 128 + rowtile) * 4096;
    const int colb = (q < 2) ? (8 * q) : (16 + 8 * (q - 2));
    #pragma unroll
    for (int i = 0; i < 8; ++i) {
      *(float4*)(pws + (rg + 16 * i) * 32 + colb)     = acc[2 * i];
      *(float4*)(pws + (rg + 16 * i) * 32 + colb + 4) = acc[2 * i + 1];
    }
  }
}

__global__ __launch_bounds__(64) void epi_k(
    const float* __restrict__ pbase, const float* __restrict__ br,
    const float* __restrict__ bn, const float* __restrict__ eps,
    float* __restrict__ out, float* __restrict__ auxs) {
  const int lane = threadIdx.x;
  const int bid  = blockIdx.x;
  const int row_g = bid * 64 + lane;
  const int rowtile = row_g >> 7;
  const int row_l   = row_g & 127;

  float c[32];
  #pragma unroll
  for (int g = 0; g < 8; ++g) {
    float4 p0 = *(const float4*)(pbase + (size_t)(0 * 128 + rowtile) * 4096 + row_l * 32 + g * 4);
    float4 p1 = *(const float4*)(pbase + (size_t)(1 * 128 + rowtile) * 4096 + row_l * 32 + g * 4);
    c[g * 4 + 0] = p0.x + p1.x; c[g * 4 + 1] = p0.y + p1.y;
    c[g * 4 + 2] = p0.z + p1.z; c[g * 4 + 3] = p0.w + p1.w;
  }

  float brv[16], bnv[16], ev[16];
  #pragma unroll
  for (int g = 0; g < 4; ++g) {
    *(float4*)(brv + g * 4) = *(const float4*)(br + g * 4);
    *(float4*)(bnv + g * 4) = *(const float4*)(bn + g * 4);
    *(float4*)(ev  + g * 4) = *(const float4*)(eps + (size_t)row_g * NEXP + g * 4);
  }

  float s[16];
  #pragma unroll
  for (int e = 0; e < 16; ++e) {
    float lg = c[e] + brv[e];
    float nz = c[16 + e] + bnv[e];
    float sp = fmaxf(nz, 0.f) + log1pf(expf(-fabsf(nz)));  // stable softplus
    s[e] = lg + ev[e] * sp;                                 // TEMPERATURE == 1
  }

  // top-2 (ties -> lowest index, matching lax.top_k)
  float b1 = s[0]; int i1 = 0;
  #pragma unroll
  for (int e = 1; e < 16; ++e) { if (s[e] > b1) { b1 = s[e]; i1 = e; } }
  float b2 = -INFINITY; int i2 = 0;
  #pragma unroll
  for (int e = 0; e < 16; ++e) { if (e != i1 && s[e] > b2) { b2 = s[e]; i2 = e; } }

  float t2 = expf(b2 - b1);
  float p1 = 1.f / (1.f + t2);
  float p2 = t2 / (1.f + t2);

  float v[16];
  #pragma unroll
  for (int e = 0; e < 16; ++e)
    v[e] = (e == i1) ? p1 : ((e == i2) ? p2 : 0.f);

  float* orow = out + (size_t)row_g * NEXP;
  *(float4*)(orow + 0)  = make_float4(v[0], v[1], v[2], v[3]);
  *(float4*)(orow + 4)  = make_float4(v[4], v[5], v[6], v[7]);
  *(float4*)(orow + 8)  = make_float4(v[8], v[9], v[10], v[11]);
  *(float4*)(orow + 12) = make_float4(v[12], v[13], v[14], v[15]);

  float* oidx = out + IDX_OFF + (size_t)row_g * 2;
  *(float2*)oidx = make_float2((float)i1, (float)i2);

  // per-block expert-prob sums over 64 rows (full-wave butterfly)
  #pragma unroll
  for (int m = 1; m < 64; m <<= 1) {
    #pragma unroll
    for (int e = 0; e < 16; ++e) v[e] += __shfl_xor(v[e], m, 64);
  }
  if (lane == 0) {
    float* ap = auxs + (size_t)bid * 16;
    *(float4*)(ap + 0)  = make_float4(v[0], v[1], v[2], v[3]);
    *(float4*)(ap + 4)  = make_float4(v[4], v[5], v[6], v[7]);
    *(float4*)(ap + 8)  = make_float4(v[8], v[9], v[10], v[11]);
    *(float4*)(ap + 12) = make_float4(v[12], v[13], v[14], v[15]);
  }
}

__global__ void router_aux_k(const float* __restrict__ auxs, float* __restrict__ out_aux) {
  __shared__ float red[16][17];
  __shared__ float sq[16];
  const int t = threadIdx.x;
  const int e = t & 15;
  const int g = t >> 4;
  float ssum = 0.f;
  #pragma unroll
  for (int b = 0; b < 16; ++b) ssum += auxs[(size_t)(g * 16 + b) * 16 + e];
  red[g][e] = ssum;
  __syncthreads();
  if (t < 16) {
    float tot = 0.f;
    #pragma unroll
    for (int gg = 0; gg < 16; ++gg) tot += red[gg][t];
    float diff = tot * (1.f / 16384.f) - 0.0625f;
    sq[t] = diff * diff;
  }
  __syncthreads();
  if (t == 0) {
    float a = 0.f;
    #pragma unroll
    for (int i = 0; i < 16; ++i) a += sq[i];
    *out_aux = a;
  }
}

extern "C" void kernel_launch(void* const* d_in, const int* in_sizes, int n_in,
                              void* d_out, int out_size, void* d_ws, size_t ws_size,
                              hipStream_t stream) {
  const float* x   = (const float*)d_in[0];
  const float* wr  = (const float*)d_in[1];
  const float* br  = (const float*)d_in[2];
  const float* wn  = (const float*)d_in[3];
  const float* bn  = (const float*)d_in[4];
  const float* eps = (const float*)d_in[5];
  float* out = (float*)d_out;

  float* wsf   = (float*)d_ws;
  float* auxs  = wsf;            // 256*16 floats
  float* pbase = wsf + 4096;     // 2*128*4096 floats = 4 MB

  gemv_k<<<256, 512, 0, stream>>>(x, wr, wn, pbase);
  epi_k<<<256, 64, 0, stream>>>(pbase, br, bn, eps, out, auxs);
  router_aux_k<<<1, 256, 0, stream>>>(auxs, out + AUX_OFF);
}

// Round 15
// 87.115 us; speedup vs baseline: 1.1681x; 1.1681x over previous
//
#include <hip/hip_runtime.h>
#include <math.h>

// NoisyTopkRouter: B=4 S=4096 D=2048 E=16 K=2, TEMPERATURE=1. rows = 16384.
// out layout (fp32): router_output [16384*16] | indices-as-float [16384*2] | aux_loss [1]
// Round 15: r9 (best: 52us, VGPR 72) + vmcnt-FIFO-safe issue order ONLY.
//  Theory: r9 issues x-HBM prefetch at chunk top; every later W-refill wait
//  (in-order vmcnt FIFO) transitively drains the ~600-900cy x load -> serial
//  HBM exposure every chunk = the 78-83us invariant across r9-r13.
//  Fix: issue xp for chunk k+2 at MID-chunk k (after gg1 refill). All W-waits
//  then target loads OLDER than xp (drain nothing newer); xp's first drain is
//  3 phases (~1500 wall cyc) later -> full latency cover. ds_write moved to
//  mid-chunk (writes the idle dbuf half; same-wave DS ordering = correct).
//  Geometry/reduce/epilogue byte-identical to r9. One-variable change.

#define DDIM 2048
#define NEXP 16
#define RPB 64             // rows per block
#define WAVE_D 256         // d-slice per wave (8 waves cover 2048)
#define NCHNK 16           // 16-d chunks per wave slice
#define IDX_OFF 262144
#define AUX_OFF 294912
#define NBLK 256

__global__ __launch_bounds__(512) void router_main_k(
    const float* __restrict__ x, const float* __restrict__ wr,
    const float* __restrict__ br, const float* __restrict__ wn,
    const float* __restrict__ bn, const float* __restrict__ eps,
    float* __restrict__ out, float* __restrict__ wsp) {
  __shared__ float smem[16384];  // 64KB: 8 x-regions [2][64][16] / reduce [8][64][32]

  const int tid  = threadIdx.x;
  const int wave = tid >> 6;
  const int lane = tid & 63;
  const int rg   = lane >> 3;        // 0..7 -> rows {rg + 8i}, i = 0..7
  const int q    = lane & 7;         // col group: q<4 route cols 4q..; q>=4 noise
  const int sw   = rg >> 1;          // read-side LDS quad swizzle
  const int row_base = blockIdx.x * RPB;

  float* xreg = smem + wave * 2048;  // [2][64][16] dbuf x slice

  // staging: lane -> (srow = lane>>2, quad = lane&3); rows srow+16t, t=0..3
  const int srow  = lane >> 2;
  const int squad = lane & 3;
  const float* xsrc = x + (size_t)(row_base + srow) * DDIM + wave * WAVE_D + squad * 4;
  const int lwoff = srow * 16 + ((squad ^ ((srow >> 1) & 3)) << 2);  // +256 per t

  const float* wbase = (q < 4 ? wr : wn) + (size_t)(wave * WAVE_D) * NEXP + (q & 3) * 4;

  float4 acc[8];
  #pragma unroll
  for (int i = 0; i < 8; ++i) acc[i] = make_float4(0.f, 0.f, 0.f, 0.f);

  float4 wp0[4], wp1[4];   // ping-pong W pipeline (named arrays -> static regs)
  float4 xp[4];

  // ---- prologue: W g0,g1; x chunk0 -> buf0; x chunk1 in flight ----
  #pragma unroll
  for (int j = 0; j < 4; ++j) wp0[j] = *(const float4*)(wbase + j * NEXP);
  #pragma unroll
  for (int j = 0; j < 4; ++j) wp1[j] = *(const float4*)(wbase + 64 + j * NEXP);
  #pragma unroll
  for (int t = 0; t < 4; ++t) xp[t] = *(const float4*)(xsrc + (size_t)t * 16 * DDIM);
  #pragma unroll
  for (int t = 0; t < 4; ++t) *(float4*)(xreg + lwoff + t * 256) = xp[t];
  #pragma unroll
  for (int t = 0; t < 4; ++t) xp[t] = *(const float4*)(xsrc + (size_t)t * 16 * DDIM + 16);

#define FMA_ROW(WPA, GG, i) { \
    const float4 xv = *(const float4*)(xb + (rg + 8 * (i)) * 16 + (((GG) ^ sw) << 2)); \
    acc[i].x = fmaf(xv.w, WPA[3].x, fmaf(xv.z, WPA[2].x, fmaf(xv.y, WPA[1].x, fmaf(xv.x, WPA[0].x, acc[i].x)))); \
    acc[i].y = fmaf(xv.w, WPA[3].y, fmaf(xv.z, WPA[2].y, fmaf(xv.y, WPA[1].y, fmaf(xv.x, WPA[0].y, acc[i].y)))); \
    acc[i].z = fmaf(xv.w, WPA[3].z, fmaf(xv.z, WPA[2].z, fmaf(xv.y, WPA[1].z, fmaf(xv.x, WPA[0].z, acc[i].z)))); \
    acc[i].w = fmaf(xv.w, WPA[3].w, fmaf(xv.z, WPA[2].w, fmaf(xv.y, WPA[1].w, fmaf(xv.x, WPA[0].w, acc[i].w)))); }

  for (int k = 0; k < NCHNK; ++k) {
    const float* xb = xreg + (k & 1) * 1024;
    // gg0: consume wp0 (g4k), refill wp0 <- g(4k+2)  [<=62, unguarded]
    #pragma unroll
    for (int i = 0; i < 8; ++i) FMA_ROW(wp0, 0, i);
    { const float* wl = wbase + (size_t)(4 * k + 2) * 64;
      #pragma unroll
      for (int j = 0; j < 4; ++j) wp0[j] = *(const float4*)(wl + j * NEXP); }
    // gg1: consume wp1 (g4k+1), refill wp1 <- g(4k+3)  [<=63, unguarded]
    #pragma unroll
    for (int i = 0; i < 8; ++i) FMA_ROW(wp1, 1, i);
    { const float* wl = wbase + (size_t)(4 * k + 3) * 64;
      #pragma unroll
      for (int j = 0; j < 4; ++j) wp1[j] = *(const float4*)(wl + j * NEXP); }
    // ---- mid-chunk staging: write chunk k+1 (xp, loaded ~1.5 chunks ago ->
    //      its vmcnt wait drains only chunk-old loads), then issue chunk k+2
    //      AFTER this chunk's gg0/gg1 W refills (FIFO: later W-waits are for
    //      OLDER entries -> never drain xp; first xp drain = next chunk's gg0
    //      wait, 3 phases away) ----
    if (k + 1 < NCHNK) {
      float* xw = xreg + ((k + 1) & 1) * 1024;
      #pragma unroll
      for (int t = 0; t < 4; ++t) *(float4*)(xw + lwoff + t * 256) = xp[t];
    }
    if (k + 2 < NCHNK) {
      #pragma unroll
      for (int t = 0; t < 4; ++t)
        xp[t] = *(const float4*)(xsrc + (size_t)t * 16 * DDIM + (k + 2) * 16);
    }
    // gg2: consume wp0 (g4k+2: oldest outstanding -> drains nothing newer),
    //      refill wp0 <- g(4k+4) (guarded)
    #pragma unroll
    for (int i = 0; i < 8; ++i) FMA_ROW(wp0, 2, i);
    if (k + 1 < NCHNK) {
      const float* wl = wbase + (size_t)(4 * k + 4) * 64;
      #pragma unroll
      for (int j = 0; j < 4; ++j) wp0[j] = *(const float4*)(wl + j * NEXP);
    }
    // gg3: consume wp1 (g4k+3: oldest), refill wp1 <- g(4k+5) (guarded)
    #pragma unroll
    for (int i = 0; i < 8; ++i) FMA_ROW(wp1, 3, i);
    if (k + 1 < NCHNK) {
      const float* wl = wbase + (size_t)(4 * k + 5) * 64;
      #pragma unroll
      for (int j = 0; j < 4; ++j) wp1[j] = *(const float4*)(wl + j * NEXP);
    }
  }

  // ---- 8-wave tree reduce over [64][32] regions (swizzled col q^rg) ----
  const int psw = (q ^ rg) << 2;

#define DUMP_R(Rg) { float* pr = smem + (Rg) * 2048; \
    _Pragma("unroll") for (int i = 0; i < 8; ++i) \
      *(float4*)(pr + (rg + 8 * i) * 32 + psw) = acc[i]; }
#define ADD_R(Rg) { const float* pr = smem + (Rg) * 2048; \
    _Pragma("unroll") for (int i = 0; i < 8; ++i) { \
      float4 a = *(const float4*)(pr + (rg + 8 * i) * 32 + psw); \
      acc[i].x += a.x; acc[i].y += a.y; acc[i].z += a.z; acc[i].w += a.w; } }

  __syncthreads();
  if (wave >= 4) DUMP_R(wave - 4);
  __syncthreads();
  if (wave < 4)  ADD_R(wave);
  __syncthreads();
  if (wave >= 2 && wave < 4) DUMP_R(wave - 2);
  __syncthreads();
  if (wave < 2)  ADD_R(wave);
  __syncthreads();
  if (wave == 1) DUMP_R(0);
  __syncthreads();

  // ---- wave 0: final add; per-row epilogue (64 rows on 64 lanes) ----
  if (wave == 0) {
    ADD_R(0);
    DUMP_R(0);   // same-wave ds_write -> ds_read: compiler inserts lgkm waits

    const int row_l = lane;
    const int row_g = row_base + row_l;
    float c[32];
    #pragma unroll
    for (int g = 0; g < 8; ++g) {
      float4 a = *(const float4*)(smem + row_l * 32 + ((g ^ (row_l & 7)) << 2));
      c[g * 4 + 0] = a.x; c[g * 4 + 1] = a.y; c[g * 4 + 2] = a.z; c[g * 4 + 3] = a.w;
    }

    float brv[16], bnv[16], ev[16];
    #pragma unroll
    for (int g = 0; g < 4; ++g) {
      *(float4*)(brv + g * 4) = *(const float4*)(br + g * 4);
      *(float4*)(bnv + g * 4) = *(const float4*)(bn + g * 4);
      *(float4*)(ev  + g * 4) = *(const float4*)(eps + (size_t)row_g * NEXP + g * 4);
    }

    float s[16];
    #pragma unroll
    for (int e = 0; e < 16; ++e) {
      float lg = c[e] + brv[e];
      float nz = c[16 + e] + bnv[e];
      float sp = fmaxf(nz, 0.f) + log1pf(expf(-fabsf(nz)));  // stable softplus
      s[e] = lg + ev[e] * sp;                                 // TEMPERATURE == 1
    }

    // top-2 (ties -> lowest index, matching lax.top_k)
    float b1 = s[0]; int i1 = 0;
    #pragma unroll
    for (int e = 1; e < 16; ++e) { if (s[e] > b1) { b1 = s[e]; i1 = e; } }
    float b2 = -INFINITY; int i2 = 0;
    #pragma unroll
    for (int e = 0; e < 16; ++e) { if (e != i1 && s[e] > b2) { b2 = s[e]; i2 = e; } }

    float t2 = expf(b2 - b1);
    float p1 = 1.f / (1.f + t2);
    float p2 = t2 / (1.f + t2);

    float v[16];
    #pragma unroll
    for (int e = 0; e < 16; ++e)
      v[e] = (e == i1) ? p1 : ((e == i2) ? p2 : 0.f);

    float* orow = out + (size_t)row_g * NEXP;
    *(float4*)(orow + 0)  = make_float4(v[0], v[1], v[2], v[3]);
    *(float4*)(orow + 4)  = make_float4(v[4], v[5], v[6], v[7]);
    *(float4*)(orow + 8)  = make_float4(v[8], v[9], v[10], v[11]);
    *(float4*)(orow + 12) = make_float4(v[12], v[13], v[14], v[15]);

    float* oidx = out + IDX_OFF + (size_t)row_g * 2;
    *(float2*)oidx = make_float2((float)i1, (float)i2);

    // per-block expert-prob sums over 64 rows (full-wave butterfly)
    #pragma unroll
    for (int m = 1; m < 64; m <<= 1) {
      #pragma unroll
      for (int e = 0; e < 16; ++e) v[e] += __shfl_xor(v[e], m, 64);
    }
    if (lane == 0) {
      float* wpo = wsp + (size_t)blockIdx.x * 16;
      *(float4*)(wpo + 0)  = make_float4(v[0], v[1], v[2], v[3]);
      *(float4*)(wpo + 4)  = make_float4(v[4], v[5], v[6], v[7]);
      *(float4*)(wpo + 8)  = make_float4(v[8], v[9], v[10], v[11]);
      *(float4*)(wpo + 12) = make_float4(v[12], v[13], v[14], v[15]);
    }
  }
}

__global__ void router_aux_k(const float* __restrict__ wsp, float* __restrict__ out_aux) {
  __shared__ float red[16][17];
  __shared__ float sq[16];
  const int t = threadIdx.x;
  const int e = t & 15;
  const int g = t >> 4;
  float ssum = 0.f;
  #pragma unroll
  for (int b = 0; b < 16; ++b) ssum += wsp[(size_t)(g * 16 + b) * 16 + e];
  red[g][e] = ssum;
  __syncthreads();
  if (t < 16) {
    float tot = 0.f;
    #pragma unroll
    for (int gg = 0; gg < 16; ++gg) tot += red[gg][t];
    float diff = tot * (1.f / 16384.f) - 0.0625f;
    sq[t] = diff * diff;
  }
  __syncthreads();
  if (t == 0) {
    float a = 0.f;
    #pragma unroll
    for (int i = 0; i < 16; ++i) a += sq[i];
    *out_aux = a;
  }
}

extern "C" void kernel_launch(void* const* d_in, const int* in_sizes, int n_in,
                              void* d_out, int out_size, void* d_ws, size_t ws_size,
                              hipStream_t stream) {
  const float* x   = (const float*)d_in[0];
  const float* wr  = (const float*)d_in[1];
  const float* br  = (const float*)d_in[2];
  const float* wn  = (const float*)d_in[3];
  const float* bn  = (const float*)d_in[4];
  const float* eps = (const float*)d_in[5];
  float* out = (float*)d_out;
  float* wsp = (float*)d_ws;  // 256 blocks * 16 floats = 16 KB partials

  router_main_k<<<NBLK, 512, 0, stream>>>(x, wr, bn ? br : br, wn, bn, eps, out, wsp);
  router_aux_k<<<1, 256, 0, stream>>>(wsp, out + AUX_OFF);
}

// Round 17
// 78.923 us; speedup vs baseline: 1.2893x; 1.1038x over previous
//
#include <hip/hip_runtime.h>
#include <math.h>

// NoisyTopkRouter: B=4 S=4096 D=2048 E=16 K=2, TEMPERATURE=1. rows = 16384.
// out layout (fp32): router_output [16384*16] | indices-as-float [16384*2] | aux_loss [1]
// Round 17: r16 (exact-fp32 GEMM via bf16 MFMA 3-way split) with the workspace
// overlap FIXED: wt = 3*32*2048 bf16 = 98304 FLOATS (r16 mis-sized it as 49152,
// so pbase slice-0 writes clobbered wm/wl mid-kernel -> absmax 1.0).
//  math recap: x = xh+xm+xl, w = wh+wm+wl (Sterbenz-exact bf16 splits);
//  acc = xh(wh+wm+wl) + xm(wh+wm) + xl*wh -> |err| ~5e-6 absolute (fp32 class).
//  k0 conv: W -> wt[level3][ecol32][k2048] bf16 (transposed, B-frags contiguous).
//  k1 gemm: wave = 16-row tile x K/4 slice; per K=32 step: 2 x-loads + 6
//    wt-loads + split + 12 MFMA; no LDS/barriers in loop. C-frag (m89:
//    col=lane&15, row=(lane>>4)*4+reg) staged via LDS tile -> coalesced
//    partial writes. 36KB LDS -> 4-block budget target -> 128 VGPR (~75 demand).
//  k2 epilogue + k3 aux: r13-proven.

#define NEXP 16
#define IDX_OFF 262144
#define AUX_OFF 294912
#define WT_FLOATS 98304     // 3*32*2048 shorts / 2

typedef __attribute__((ext_vector_type(8))) short short8v;
typedef __attribute__((ext_vector_type(4))) float f32x4;

// ---- k0: W converter: wr/wn [2048][16] fp32 -> wt[3][32][2048] bf16 ----
__global__ __launch_bounds__(256) void conv_k(
    const float* __restrict__ wr, const float* __restrict__ wn,
    unsigned short* __restrict__ wt) {
  const int e  = blockIdx.x >> 3;                       // 0..31
  const int k  = (blockIdx.x & 7) * 256 + threadIdx.x;  // 0..2047
  const float* src = (e < 16) ? (wr + e) : (wn + (e - 16));
  float f = src[(size_t)k * 16];
  unsigned u  = __float_as_uint(f);
  unsigned hu = u & 0xffff0000u;
  float r1 = f - __uint_as_float(hu);
  unsigned mu = __float_as_uint(r1) & 0xffff0000u;
  float r2 = r1 - __uint_as_float(mu);
  unsigned lu = __float_as_uint(r2);
  wt[0 * 65536 + e * 2048 + k] = (unsigned short)(hu >> 16);
  wt[1 * 65536 + e * 2048 + k] = (unsigned short)(mu >> 16);
  wt[2 * 65536 + e * 2048 + k] = (unsigned short)(lu >> 16);
}

// ---- k1: MFMA gemm, split-K ----
template<int NS>
__global__ __launch_bounds__(256) void gemm_k(
    const float* __restrict__ x, const unsigned short* __restrict__ wt,
    float* __restrict__ pbase) {
  constexpr int KS = 2048 / NS;       // K per slice
  constexpr int NSTEP = KS / 32;      // K-steps
  __shared__ float smem[9216];        // 36KB: out-staging + VGPR-budget pin

  const int tid  = threadIdx.x;
  const int wave = tid >> 6;
  const int lane = tid & 63;
  const int l15  = lane & 15;
  const int kg   = lane >> 4;         // k-group 0..3 (8 k each)
  const int rowblk = blockIdx.x / NS; // 0..255
  const int slice  = blockIdx.x % NS;

  const int row = rowblk * 64 + wave * 16 + l15;
  const float* xp = x + (size_t)row * 2048 + slice * KS + kg * 8;

  // wt bases for 6 B-frags: (level, coltile); coltile0 = route, 1 = noise
  const size_t wl_off = (size_t)slice * KS + kg * 8;
  const unsigned short* ph0 = wt + 0 * 65536 + (l15)      * 2048 + wl_off;
  const unsigned short* ph1 = wt + 0 * 65536 + (16 + l15) * 2048 + wl_off;
  const unsigned short* pm0 = wt + 1 * 65536 + (l15)      * 2048 + wl_off;
  const unsigned short* pm1 = wt + 1 * 65536 + (16 + l15) * 2048 + wl_off;
  const unsigned short* pl0 = wt + 2 * 65536 + (l15)      * 2048 + wl_off;
  const unsigned short* pl1 = wt + 2 * 65536 + (16 + l15) * 2048 + wl_off;

  f32x4 accR = {0.f, 0.f, 0.f, 0.f};
  f32x4 accN = {0.f, 0.f, 0.f, 0.f};

  for (int s = 0; s < NSTEP; ++s) {
    // x: 8 fp32 (this lane's row, k-group)
    float4 xa = *(const float4*)(xp + s * 32);
    float4 xb = *(const float4*)(xp + s * 32 + 4);
    // B-frags: 6 x 16B bf16x8
    short8v bh0 = *(const short8v*)(ph0 + (size_t)s * 32);
    short8v bh1 = *(const short8v*)(ph1 + (size_t)s * 32);
    short8v bm0 = *(const short8v*)(pm0 + (size_t)s * 32);
    short8v bm1 = *(const short8v*)(pm1 + (size_t)s * 32);
    short8v bl0 = *(const short8v*)(pl0 + (size_t)s * 32);
    short8v bl1 = *(const short8v*)(pl1 + (size_t)s * 32);
    // 3-way exact split of x
    short8v xh, xm, xl;
    float f[8] = {xa.x, xa.y, xa.z, xa.w, xb.x, xb.y, xb.z, xb.w};
    #pragma unroll
    for (int j = 0; j < 8; ++j) {
      unsigned u  = __float_as_uint(f[j]);
      unsigned hu = u & 0xffff0000u;
      float r1 = f[j] - __uint_as_float(hu);
      unsigned mu = __float_as_uint(r1) & 0xffff0000u;
      float r2 = r1 - __uint_as_float(mu);
      unsigned lu = __float_as_uint(r2);
      xh[j] = (short)(hu >> 16);
      xm[j] = (short)(mu >> 16);
      xl[j] = (short)(lu >> 16);
    }
    // 6 products per coltile (hh, mh, lh, hm, mm, hl)
    accR = __builtin_amdgcn_mfma_f32_16x16x32_bf16(xh, bh0, accR, 0, 0, 0);
    accN = __builtin_amdgcn_mfma_f32_16x16x32_bf16(xh, bh1, accN, 0, 0, 0);
    accR = __builtin_amdgcn_mfma_f32_16x16x32_bf16(xm, bh0, accR, 0, 0, 0);
    accN = __builtin_amdgcn_mfma_f32_16x16x32_bf16(xm, bh1, accN, 0, 0, 0);
    accR = __builtin_amdgcn_mfma_f32_16x16x32_bf16(xl, bh0, accR, 0, 0, 0);
    accN = __builtin_amdgcn_mfma_f32_16x16x32_bf16(xl, bh1, accN, 0, 0, 0);
    accR = __builtin_amdgcn_mfma_f32_16x16x32_bf16(xh, bm0, accR, 0, 0, 0);
    accN = __builtin_amdgcn_mfma_f32_16x16x32_bf16(xh, bm1, accN, 0, 0, 0);
    accR = __builtin_amdgcn_mfma_f32_16x16x32_bf16(xm, bm0, accR, 0, 0, 0);
    accN = __builtin_amdgcn_mfma_f32_16x16x32_bf16(xm, bm1, accN, 0, 0, 0);
    accR = __builtin_amdgcn_mfma_f32_16x16x32_bf16(xh, bl0, accR, 0, 0, 0);
    accN = __builtin_amdgcn_mfma_f32_16x16x32_bf16(xh, bl1, accN, 0, 0, 0);
  }

  // C-frag (col=lane&15, row=(lane>>4)*4+j) -> LDS tile [16][36] -> coalesced out
  float* tile = smem + wave * 576;
  #pragma unroll
  for (int j = 0; j < 4; ++j) {
    tile[(kg * 4 + j) * 36 + l15]      = accR[j];
    tile[(kg * 4 + j) * 36 + 16 + l15] = accN[j];
  }
  // same-wave cross-lane handoff through LDS (DS pipe in-order per wave;
  // compiler inserts the lgkm wait for the register dependency)
  float* po = pbase + (size_t)slice * 524288 + ((size_t)rowblk * 64 + wave * 16) * 32;
  #pragma unroll
  for (int u = 0; u < 2; ++u) {
    const int idx = lane * 8 + u * 4;
    const int r = idx >> 5;
    const int c = idx & 31;
    float4 v = *(const float4*)(tile + r * 36 + c);
    *(float4*)(po + idx) = v;
  }
}

// ---- k2: epilogue (r13-proven) ----
template<int NS>
__global__ __launch_bounds__(64) void epi_k(
    const float* __restrict__ pbase, const float* __restrict__ br,
    const float* __restrict__ bn, const float* __restrict__ eps,
    float* __restrict__ out, float* __restrict__ auxs) {
  const int lane = threadIdx.x;
  const int bid  = blockIdx.x;
  const int row_g = bid * 64 + lane;

  float c[32];
  #pragma unroll
  for (int g = 0; g < 8; ++g) {
    float4 a = make_float4(0.f, 0.f, 0.f, 0.f);
    #pragma unroll
    for (int s = 0; s < NS; ++s) {
      float4 p = *(const float4*)(pbase + (size_t)s * 524288 + (size_t)row_g * 32 + g * 4);
      a.x += p.x; a.y += p.y; a.z += p.z; a.w += p.w;
    }
    c[g * 4 + 0] = a.x; c[g * 4 + 1] = a.y; c[g * 4 + 2] = a.z; c[g * 4 + 3] = a.w;
  }

  float brv[16], bnv[16], ev[16];
  #pragma unroll
  for (int g = 0; g < 4; ++g) {
    *(float4*)(brv + g * 4) = *(const float4*)(br + g * 4);
    *(float4*)(bnv + g * 4) = *(const float4*)(bn + g * 4);
    *(float4*)(ev  + g * 4) = *(const float4*)(eps + (size_t)row_g * NEXP + g * 4);
  }

  float s[16];
  #pragma unroll
  for (int e = 0; e < 16; ++e) {
    float lg = c[e] + brv[e];
    float nz = c[16 + e] + bnv[e];
    float sp = fmaxf(nz, 0.f) + log1pf(expf(-fabsf(nz)));  // stable softplus
    s[e] = lg + ev[e] * sp;                                 // TEMPERATURE == 1
  }

  // top-2 (ties -> lowest index, matching lax.top_k)
  float b1 = s[0]; int i1 = 0;
  #pragma unroll
  for (int e = 1; e < 16; ++e) { if (s[e] > b1) { b1 = s[e]; i1 = e; } }
  float b2 = -INFINITY; int i2 = 0;
  #pragma unroll
  for (int e = 0; e < 16; ++e) { if (e != i1 && s[e] > b2) { b2 = s[e]; i2 = e; } }

  float t2 = expf(b2 - b1);
  float p1 = 1.f / (1.f + t2);
  float p2 = t2 / (1.f + t2);

  float v[16];
  #pragma unroll
  for (int e = 0; e < 16; ++e)
    v[e] = (e == i1) ? p1 : ((e == i2) ? p2 : 0.f);

  float* orow = out + (size_t)row_g * NEXP;
  *(float4*)(orow + 0)  = make_float4(v[0], v[1], v[2], v[3]);
  *(float4*)(orow + 4)  = make_float4(v[4], v[5], v[6], v[7]);
  *(float4*)(orow + 8)  = make_float4(v[8], v[9], v[10], v[11]);
  *(float4*)(orow + 12) = make_float4(v[12], v[13], v[14], v[15]);

  float* oidx = out + IDX_OFF + (size_t)row_g * 2;
  *(float2*)oidx = make_float2((float)i1, (float)i2);

  #pragma unroll
  for (int m = 1; m < 64; m <<= 1) {
    #pragma unroll
    for (int e = 0; e < 16; ++e) v[e] += __shfl_xor(v[e], m, 64);
  }
  if (lane == 0) {
    float* ap = auxs + (size_t)bid * 16;
    *(float4*)(ap + 0)  = make_float4(v[0], v[1], v[2], v[3]);
    *(float4*)(ap + 4)  = make_float4(v[4], v[5], v[6], v[7]);
    *(float4*)(ap + 8)  = make_float4(v[8], v[9], v[10], v[11]);
    *(float4*)(ap + 12) = make_float4(v[12], v[13], v[14], v[15]);
  }
}

__global__ void router_aux_k(const float* __restrict__ auxs, float* __restrict__ out_aux) {
  __shared__ float red[16][17];
  __shared__ float sq[16];
  const int t = threadIdx.x;
  const int e = t & 15;
  const int g = t >> 4;
  float ssum = 0.f;
  #pragma unroll
  for (int b = 0; b < 16; ++b) ssum += auxs[(size_t)(g * 16 + b) * 16 + e];
  red[g][e] = ssum;
  __syncthreads();
  if (t < 16) {
    float tot = 0.f;
    #pragma unroll
    for (int gg = 0; gg < 16; ++gg) tot += red[gg][t];
    float diff = tot * (1.f / 16384.f) - 0.0625f;
    sq[t] = diff * diff;
  }
  __syncthreads();
  if (t == 0) {
    float a = 0.f;
    #pragma unroll
    for (int i = 0; i < 16; ++i) a += sq[i];
    *out_aux = a;
  }
}

extern "C" void kernel_launch(void* const* d_in, const int* in_sizes, int n_in,
                              void* d_out, int out_size, void* d_ws, size_t ws_size,
                              hipStream_t stream) {
  const float* x   = (const float*)d_in[0];
  const float* wr  = (const float*)d_in[1];
  const float* br  = (const float*)d_in[2];
  const float* wn  = (const float*)d_in[3];
  const float* bn  = (const float*)d_in[4];
  const float* eps = (const float*)d_in[5];
  float* out = (float*)d_out;

  float* wsf = (float*)d_ws;
  float* auxs = wsf;                                   // 4096 floats
  unsigned short* wt = (unsigned short*)(wsf + 4096);  // 3*32*2048 bf16 = 98304 floats
  float* pbase = wsf + 4096 + WT_FLOATS;               // NS*524288 floats

  const size_t need4 = (size_t)(4096 + WT_FLOATS + 4 * 524288) * 4;
  const size_t need2 = (size_t)(4096 + WT_FLOATS + 2 * 524288) * 4;

  conv_k<<<256, 256, 0, stream>>>(wr, wn, wt);
  if (ws_size >= need4) {
    gemm_k<4><<<1024, 256, 0, stream>>>(x, wt, pbase);
    epi_k<4><<<256, 64, 0, stream>>>(pbase, br, bn, eps, out, auxs);
  } else if (ws_size >= need2) {
    gemm_k<2><<<512, 256, 0, stream>>>(x, wt, pbase);
    epi_k<2><<<256, 64, 0, stream>>>(pbase, br, bn, eps, out, auxs);
  } else {
    gemm_k<1><<<256, 256, 0, stream>>>(x, wt, pbase);
    epi_k<1><<<256, 64, 0, stream>>>(pbase, br, bn, eps, out, auxs);
  }
  router_aux_k<<<1, 256, 0, stream>>>(auxs, out + AUX_OFF);
}